// Round 1
// baseline (2994.255 us; speedup 1.0000x reference)
//
#include <hip/hip_runtime.h>
#include <hip/hip_bf16.h>
#include <stdint.h>

namespace {

constexpr int B  = 16;
constexpr int C  = 512;
constexpr int C8 = 64;
constexpr int V  = 96;
constexpr int T  = 96;
constexpr int VT = V * T;        // 9216
constexpr int NL = 2 * V;        // 192 logits per (b,v,t)
constexpr int CV = C * V;        // 49152

typedef unsigned short u16;
typedef unsigned int   u32;

__device__ __forceinline__ float bf2f(u16 h) {
  return __uint_as_float(((u32)h) << 16);
}
__device__ __forceinline__ u16 f2bf(float f) {
  u32 u = __float_as_uint(f);
  return (u16)((u + 0x7fffu + ((u >> 16) & 1u)) >> 16);  // RNE
}

// ---------------- KT: x[b][c][v][t] f32 -> xT[b][t][c][v] bf16 ----------------
__global__ __launch_bounds__(256) void kt_transpose(
    const float* __restrict__ x, u16* __restrict__ xT) {
  __shared__ float tile[32][33];
  int b = blockIdx.z, c = blockIdx.y;
  int v0 = (blockIdx.x % 3) * 32, t0 = (blockIdx.x / 3) * 32;
  int col = threadIdx.x & 31, r = threadIdx.x >> 5;
  const float* src = x + (size_t)(b * C + c) * VT;
#pragma unroll
  for (int k = 0; k < 4; ++k) {
    int vr = v0 + r + 8 * k;
    tile[r + 8 * k][col] = src[vr * T + t0 + col];
  }
  __syncthreads();
  u16* dst = xT + (size_t)b * T * CV + (size_t)c * V;
#pragma unroll
  for (int k = 0; k < 4; ++k) {
    int tr = t0 + r + 8 * k;
    dst[(size_t)tr * CV + v0 + col] = f2bf(tile[col][r + 8 * k]);
  }
}

// ---------------- K2: eH[b,v,t,u] = sum_c q[b,c,v,t] k[b,c,u,t], diag=-inf ----
// one block per (b,t). Phase 1: Q_t,K_t = W @ xT_t (recompute). Phase 2: Q^T K.
__global__ __launch_bounds__(256) void k_eH(
    const u16* __restrict__ xT,
    const float* __restrict__ Wq, const float* __restrict__ bq,
    const float* __restrict__ Wk, const float* __restrict__ bk,
    float* __restrict__ att) {
  __shared__ float Wl[32][132];   // Wl[cc][o], o<128 (Wq rows 0-63, Wk 64-127)
  __shared__ float Xl[32][96];    // Xl[cc][v]
  __shared__ float QK[128][96];   // staged Q (rows 0-63) / K (64-127)
  int t = blockIdx.x, b = blockIdx.y;
  int tid = threadIdx.x, tx = tid & 15, ty = tid >> 4;
  const u16* xTt = xT + (size_t)(b * T + t) * CV;
  float acc[8][6];
#pragma unroll
  for (int i = 0; i < 8; ++i)
#pragma unroll
    for (int j = 0; j < 6; ++j) acc[i][j] = 0.f;

  for (int c0 = 0; c0 < C; c0 += 32) {
    __syncthreads();
#pragma unroll
    for (int jj = 0; jj < 4; ++jj) {
      int e4 = tid + 256 * jj;              // 1024 float4s
      int row = e4 >> 3, cq = (e4 & 7) * 4;
      const float* wrow = (row < C8) ? (Wq + row * C) : (Wk + (row - C8) * C);
      float4 w = *(const float4*)&wrow[c0 + cq];
      Wl[cq + 0][row] = w.x; Wl[cq + 1][row] = w.y;
      Wl[cq + 2][row] = w.z; Wl[cq + 3][row] = w.w;
    }
#pragma unroll
    for (int jj = 0; jj < 3; ++jj) {
      int e = tid + 256 * jj;               // 768 quads of bf16
      int cc = e / 24, v4 = (e % 24) * 4;
      uint2 wv_ = *(const uint2*)(xTt + (size_t)(c0 + cc) * V + v4);
      Xl[cc][v4 + 0] = bf2f((u16)(wv_.x & 0xffffu));
      Xl[cc][v4 + 1] = bf2f((u16)(wv_.x >> 16));
      Xl[cc][v4 + 2] = bf2f((u16)(wv_.y & 0xffffu));
      Xl[cc][v4 + 3] = bf2f((u16)(wv_.y >> 16));
    }
    __syncthreads();
#pragma unroll
    for (int cc = 0; cc < 32; ++cc) {
      float wr[8], xr[6];
#pragma unroll
      for (int i = 0; i < 8; ++i) wr[i] = Wl[cc][ty * 8 + i];
#pragma unroll
      for (int j = 0; j < 6; ++j) xr[j] = Xl[cc][tx * 6 + j];
#pragma unroll
      for (int i = 0; i < 8; ++i)
#pragma unroll
        for (int j = 0; j < 6; ++j) acc[i][j] = fmaf(wr[i], xr[j], acc[i][j]);
    }
  }
  __syncthreads();
#pragma unroll
  for (int i = 0; i < 8; ++i) {
    int o = ty * 8 + i;
    float bias = (o < C8) ? bq[o] : bk[o - C8];
#pragma unroll
    for (int j = 0; j < 6; ++j) QK[o][tx * 6 + j] = acc[i][j] + bias;
  }
  __syncthreads();
  float a2[6][6];
#pragma unroll
  for (int i = 0; i < 6; ++i)
#pragma unroll
    for (int j = 0; j < 6; ++j) a2[i][j] = 0.f;
  for (int o = 0; o < C8; ++o) {
    float qv[6], kv[6];
#pragma unroll
    for (int i = 0; i < 6; ++i) qv[i] = QK[o][ty * 6 + i];
#pragma unroll
    for (int j = 0; j < 6; ++j) kv[j] = QK[C8 + o][tx * 6 + j];
#pragma unroll
    for (int i = 0; i < 6; ++i)
#pragma unroll
      for (int j = 0; j < 6; ++j) a2[i][j] = fmaf(qv[i], kv[j], a2[i][j]);
  }
#pragma unroll
  for (int i = 0; i < 6; ++i) {
    int v = ty * 6 + i;
    float* arow = att + ((size_t)(b * V + v) * T + t) * NL;
#pragma unroll
    for (int j = 0; j < 6; ++j) {
      int u = tx * 6 + j;
      arow[u] = (v == u) ? -1e30f : a2[i][j];
    }
  }
}

// ---------------- K3: eW[b,v,t,s] = sum_c q[b,c,v,t] k[b,c,v,s] ---------------
// one block per (b,v). Reads original f32 x (rows contiguous in s).
__global__ __launch_bounds__(256) void k_eW(
    const float* __restrict__ x,
    const float* __restrict__ Wq, const float* __restrict__ bq,
    const float* __restrict__ Wk, const float* __restrict__ bk,
    float* __restrict__ att) {
  __shared__ float Wl[32][132];
  __shared__ float Xl[32][96];
  __shared__ float QK[128][96];
  int v = blockIdx.x, b = blockIdx.y;
  int tid = threadIdx.x, tx = tid & 15, ty = tid >> 4;
  const float* xv = x + (size_t)b * C * VT + (size_t)v * T;  // + c*VT + s
  float acc[8][6];
#pragma unroll
  for (int i = 0; i < 8; ++i)
#pragma unroll
    for (int j = 0; j < 6; ++j) acc[i][j] = 0.f;

  for (int c0 = 0; c0 < C; c0 += 32) {
    __syncthreads();
#pragma unroll
    for (int jj = 0; jj < 4; ++jj) {
      int e4 = tid + 256 * jj;
      int row = e4 >> 3, cq = (e4 & 7) * 4;
      const float* wrow = (row < C8) ? (Wq + row * C) : (Wk + (row - C8) * C);
      float4 w = *(const float4*)&wrow[c0 + cq];
      Wl[cq + 0][row] = w.x; Wl[cq + 1][row] = w.y;
      Wl[cq + 2][row] = w.z; Wl[cq + 3][row] = w.w;
    }
#pragma unroll
    for (int jj = 0; jj < 3; ++jj) {
      int e = tid + 256 * jj;
      int cc = e / 24, s4 = (e % 24) * 4;
      float4 xx = *(const float4*)&xv[(size_t)(c0 + cc) * VT + s4];
      *(float4*)&Xl[cc][s4] = xx;
    }
    __syncthreads();
#pragma unroll
    for (int cc = 0; cc < 32; ++cc) {
      float wr[8], xr[6];
#pragma unroll
      for (int i = 0; i < 8; ++i) wr[i] = Wl[cc][ty * 8 + i];
#pragma unroll
      for (int j = 0; j < 6; ++j) xr[j] = Xl[cc][tx * 6 + j];
#pragma unroll
      for (int i = 0; i < 8; ++i)
#pragma unroll
        for (int j = 0; j < 6; ++j) acc[i][j] = fmaf(wr[i], xr[j], acc[i][j]);
    }
  }
  __syncthreads();
#pragma unroll
  for (int i = 0; i < 8; ++i) {
    int o = ty * 8 + i;
    float bias = (o < C8) ? bq[o] : bk[o - C8];
#pragma unroll
    for (int j = 0; j < 6; ++j) QK[o][tx * 6 + j] = acc[i][j] + bias;
  }
  __syncthreads();
  float a2[6][6];
#pragma unroll
  for (int i = 0; i < 6; ++i)
#pragma unroll
    for (int j = 0; j < 6; ++j) a2[i][j] = 0.f;
  for (int o = 0; o < C8; ++o) {
    float qv[6], kv[6];
#pragma unroll
    for (int i = 0; i < 6; ++i) qv[i] = QK[o][ty * 6 + i];
#pragma unroll
    for (int j = 0; j < 6; ++j) kv[j] = QK[C8 + o][tx * 6 + j];
#pragma unroll
    for (int i = 0; i < 6; ++i)
#pragma unroll
      for (int j = 0; j < 6; ++j) a2[i][j] = fmaf(qv[i], kv[j], a2[i][j]);
  }
#pragma unroll
  for (int i = 0; i < 6; ++i) {
    int tt = ty * 6 + i;
    float* arow = att + ((size_t)(b * V + v) * T + tt) * NL + V;
#pragma unroll
    for (int j = 0; j < 6; ++j) arow[tx * 6 + j] = a2[i][j];
  }
}

// ---------------- K4: softmax over 192 per (b,v,t); one wave per row ----------
__global__ __launch_bounds__(256) void k_softmax(float* __restrict__ att) {
  int wid = threadIdx.x >> 6, lane = threadIdx.x & 63;
  size_t row = (size_t)blockIdx.x * 4 + wid;
  float* p = att + row * NL;
  float a0 = p[lane], a1 = p[lane + 64], a2 = p[lane + 128];
  float m = fmaxf(a0, fmaxf(a1, a2));
#pragma unroll
  for (int off = 32; off > 0; off >>= 1) m = fmaxf(m, __shfl_xor(m, off, 64));
  float e0 = __expf(a0 - m), e1 = __expf(a1 - m), e2 = __expf(a2 - m);
  float s = e0 + e1 + e2;
#pragma unroll
  for (int off = 32; off > 0; off >>= 1) s += __shfl_xor(s, off, 64);
  float inv = 1.f / s;
  p[lane] = e0 * inv; p[lane + 64] = e1 * inv; p[lane + 128] = e2 * inv;
}

// ---------------- K5H: xT_t[c][v] <- sum_u xT_t[c][u] * aH_t[v][u] (in place) -
__global__ __launch_bounds__(256) void k_applyH(
    u16* __restrict__ xT, const float* __restrict__ att) {
  __shared__ float aT[96][98];    // aT[u][v] = aH[v][u]
  __shared__ float XcT[96][66];   // XcT[u][cc]
  int t = blockIdx.x, b = blockIdx.y;
  int tid = threadIdx.x, tx = tid & 15, ty = tid >> 4;
  const float* ab = att + ((size_t)(b * V) * T + t) * NL;  // + v*(T*NL) + u
  for (int jj = 0; jj < 36; ++jj) {
    int e = tid + 256 * jj;
    int v = e / 96, u = e % 96;
    aT[u][v] = ab[(size_t)v * (T * NL) + u];
  }
  u16* xTt = xT + (size_t)(b * T + t) * CV;
  for (int c0 = 0; c0 < C; c0 += 64) {
    __syncthreads();
#pragma unroll
    for (int jj = 0; jj < 6; ++jj) {
      int e = tid + 256 * jj;
      int cc = e / 24, u4 = (e % 24) * 4;
      uint2 wv_ = *(const uint2*)(xTt + (size_t)(c0 + cc) * V + u4);
      XcT[u4 + 0][cc] = bf2f((u16)(wv_.x & 0xffffu));
      XcT[u4 + 1][cc] = bf2f((u16)(wv_.x >> 16));
      XcT[u4 + 2][cc] = bf2f((u16)(wv_.y & 0xffffu));
      XcT[u4 + 3][cc] = bf2f((u16)(wv_.y >> 16));
    }
    __syncthreads();
    float acc2[4][6];
#pragma unroll
    for (int i = 0; i < 4; ++i)
#pragma unroll
      for (int j = 0; j < 6; ++j) acc2[i][j] = 0.f;
    for (int u = 0; u < 96; ++u) {
      float xr[4], ar[6];
#pragma unroll
      for (int i = 0; i < 4; ++i) xr[i] = XcT[u][ty * 4 + i];
#pragma unroll
      for (int j = 0; j < 6; ++j) ar[j] = aT[u][tx * 6 + j];
#pragma unroll
      for (int i = 0; i < 4; ++i)
#pragma unroll
        for (int j = 0; j < 6; ++j) acc2[i][j] = fmaf(xr[i], ar[j], acc2[i][j]);
    }
#pragma unroll
    for (int i = 0; i < 4; ++i) {
      u16* prow = xTt + (size_t)(c0 + ty * 4 + i) * V + tx * 6;
#pragma unroll
      for (int j = 0; j < 6; j += 2) {
        u32 pk = (u32)f2bf(acc2[i][j]) | ((u32)f2bf(acc2[i][j + 1]) << 16);
        *(u32*)(prow + j) = pk;
      }
    }
  }
}

// ---------------- K5W: out[b][c][v][t] = sum_s x[b][c][v][s] * aW[t][s] -------
__global__ __launch_bounds__(256) void k_applyW(
    const float* __restrict__ x, const float* __restrict__ att,
    float* __restrict__ out) {
  __shared__ float aT[96][98];    // aT[s][t] = aW[t][s]
  __shared__ float XcT[96][66];   // XcT[s][cc]
  int v = blockIdx.x, b = blockIdx.y;
  int tid = threadIdx.x, tx = tid & 15, ty = tid >> 4;
  const float* ab = att + ((size_t)(b * V + v) * T) * NL + V;  // + t*NL + s
  for (int jj = 0; jj < 36; ++jj) {
    int e = tid + 256 * jj;
    int t = e / 96, s = e % 96;
    aT[s][t] = ab[(size_t)t * NL + s];
  }
  const float* xb = x + (size_t)b * C * VT + (size_t)v * T;
  float* ob = out + (size_t)b * C * VT + (size_t)v * T;
  for (int c0 = 0; c0 < C; c0 += 64) {
    __syncthreads();
#pragma unroll
    for (int jj = 0; jj < 6; ++jj) {
      int e = tid + 256 * jj;
      int cc = e / 24, s4 = (e % 24) * 4;
      float4 xx = *(const float4*)&xb[(size_t)(c0 + cc) * VT + s4];
      XcT[s4 + 0][cc] = xx.x;
      XcT[s4 + 1][cc] = xx.y;
      XcT[s4 + 2][cc] = xx.z;
      XcT[s4 + 3][cc] = xx.w;
    }
    __syncthreads();
    float acc2[4][6];
#pragma unroll
    for (int i = 0; i < 4; ++i)
#pragma unroll
      for (int j = 0; j < 6; ++j) acc2[i][j] = 0.f;
    for (int s = 0; s < 96; ++s) {
      float xr[4], ar[6];
#pragma unroll
      for (int i = 0; i < 4; ++i) xr[i] = XcT[s][ty * 4 + i];
#pragma unroll
      for (int j = 0; j < 6; ++j) ar[j] = aT[s][tx * 6 + j];
#pragma unroll
      for (int i = 0; i < 4; ++i)
#pragma unroll
        for (int j = 0; j < 6; ++j) acc2[i][j] = fmaf(xr[i], ar[j], acc2[i][j]);
    }
#pragma unroll
    for (int i = 0; i < 4; ++i) {
      float* prow = ob + (size_t)(c0 + ty * 4 + i) * VT + tx * 6;
#pragma unroll
      for (int j = 0; j < 6; j += 2) {
        *(float2*)(prow + j) = make_float2(acc2[i][j], acc2[i][j + 1]);
      }
    }
  }
}

// ---------------- K5M: out[b][c][v][t] += xT[b][t][c][v] (bf16 holds xH) ------
__global__ __launch_bounds__(256) void k_merge(
    float* __restrict__ out, const u16* __restrict__ xT) {
  __shared__ float tile[32][33];
  int b = blockIdx.z, c = blockIdx.y;
  int v0 = (blockIdx.x % 3) * 32, t0 = (blockIdx.x / 3) * 32;
  int col = threadIdx.x & 31, r = threadIdx.x >> 5;
  const u16* src = xT + (size_t)b * T * CV + (size_t)c * V;
#pragma unroll
  for (int k = 0; k < 4; ++k) {
    int tr = t0 + r + 8 * k;
    tile[r + 8 * k][col] = bf2f(src[(size_t)tr * CV + v0 + col]);
  }
  __syncthreads();
  float* dst = out + (size_t)(b * C + c) * VT;
#pragma unroll
  for (int k = 0; k < 4; ++k) {
    int vr = v0 + r + 8 * k;
    dst[(size_t)vr * T + t0 + col] += tile[col][r + 8 * k];
  }
}

// ---------------- K6: out = gamma*(Wv@out + bv) + x, in place per p-columns ---
__global__ __launch_bounds__(256) void k_final(
    float* __restrict__ out, const float* __restrict__ x,
    const float* __restrict__ Wv, const float* __restrict__ bv,
    const float* __restrict__ gamma) {
  __shared__ float Sx[C][32];     // 64 KB: all K for this block's 32 p-columns
  __shared__ float WlT[16][132];  // Wv chunk transposed
  int pt = blockIdx.x, b = blockIdx.y;
  int p0 = pt * 32;
  int tid = threadIdx.x, tx = tid & 15, ty = tid >> 4;
  const float* xb = x + (size_t)b * C * VT;
  float* ob = out + (size_t)b * C * VT;
#pragma unroll
  for (int jj = 0; jj < 16; ++jj) {
    int e4 = tid + 256 * jj;                // 4096 float4s
    int c = e4 >> 3, p4 = (e4 & 7) * 4;
    float4 s = *(const float4*)&ob[(size_t)c * VT + p0 + p4];
    *(float4*)&Sx[c][p4] = s;
  }
  float g = gamma[0];
  for (int r = 0; r < 4; ++r) {
    float acc2[8][2];
#pragma unroll
    for (int i = 0; i < 8; ++i) { acc2[i][0] = 0.f; acc2[i][1] = 0.f; }
    for (int kc = 0; kc < 32; ++kc) {
      __syncthreads();
#pragma unroll
      for (int jj = 0; jj < 2; ++jj) {
        int e4 = tid + 256 * jj;            // 512 float4s = 128 rows x 16 cc
        int row = e4 >> 2, c4 = (e4 & 3) * 4;
        float4 w = *(const float4*)&Wv[(size_t)(r * 128 + row) * C + kc * 16 + c4];
        WlT[c4 + 0][row] = w.x; WlT[c4 + 1][row] = w.y;
        WlT[c4 + 2][row] = w.z; WlT[c4 + 3][row] = w.w;
      }
      __syncthreads();
#pragma unroll
      for (int cc = 0; cc < 16; ++cc) {
        float wr[8], x0, x1;
#pragma unroll
        for (int i = 0; i < 8; ++i) wr[i] = WlT[cc][ty * 8 + i];
        x0 = Sx[kc * 16 + cc][tx * 2 + 0];
        x1 = Sx[kc * 16 + cc][tx * 2 + 1];
#pragma unroll
        for (int i = 0; i < 8; ++i) {
          acc2[i][0] = fmaf(wr[i], x0, acc2[i][0]);
          acc2[i][1] = fmaf(wr[i], x1, acc2[i][1]);
        }
      }
    }
#pragma unroll
    for (int i = 0; i < 8; ++i) {
      int co = r * 128 + ty * 8 + i;
      float bb = bv[co];
      size_t base = (size_t)co * VT + p0 + tx * 2;
      float o0 = g * (acc2[i][0] + bb) + xb[base + 0];
      float o1 = g * (acc2[i][1] + bb) + xb[base + 1];
      *(float2*)&ob[base] = make_float2(o0, o1);
    }
  }
}

}  // namespace

extern "C" void kernel_launch(void* const* d_in, const int* in_sizes, int n_in,
                              void* d_out, int out_size, void* d_ws, size_t ws_size,
                              hipStream_t stream) {
  (void)in_sizes; (void)n_in; (void)out_size; (void)ws_size;
  const float* x     = (const float*)d_in[0];
  const float* Wq    = (const float*)d_in[1];
  const float* bq    = (const float*)d_in[2];
  const float* Wk    = (const float*)d_in[3];
  const float* bk    = (const float*)d_in[4];
  const float* Wv    = (const float*)d_in[5];
  const float* bv    = (const float*)d_in[6];
  const float* gamma = (const float*)d_in[7];
  float* out = (float*)d_out;

  // ws layout: xT bf16 [B][T][C][V] (151 MB), att f32 [B][V][T][192] (113 MB)
  u16*   xT  = (u16*)d_ws;
  float* att = (float*)((char*)d_ws + (size_t)B * T * CV * sizeof(u16));

  dim3 blk(256);
  kt_transpose<<<dim3(9, C, B), blk, 0, stream>>>(x, xT);
  k_eH      <<<dim3(T, B), blk, 0, stream>>>(xT, Wq, bq, Wk, bk, att);
  k_eW      <<<dim3(V, B), blk, 0, stream>>>(x,  Wq, bq, Wk, bk, att);
  k_softmax <<<dim3((B * V * T) / 4), blk, 0, stream>>>(att);
  k_applyH  <<<dim3(T, B), blk, 0, stream>>>(xT, att);
  k_applyW  <<<dim3(V, B), blk, 0, stream>>>(x, att, out);
  k_merge   <<<dim3(9, C, B), blk, 0, stream>>>(out, xT);
  k_final   <<<dim3(VT / 32, B), blk, 0, stream>>>(out, x, Wv, bv, gamma);
}